// Round 1
// baseline (796.407 us; speedup 1.0000x reference)
//
#include <hip/hip_runtime.h>
#include <hip/hip_bf16.h>

// Phase 2: one wave (64 lanes) per edge. Lane l handles columns 2l, 2l+1.
// Gather feature[src[e]] (coalesced 512B/wave), atomicAdd into h[dst[e]].
__global__ __launch_bounds__(256) void gcn_scatter_kernel(
    const float* __restrict__ feature,
    const int* __restrict__ src,
    const int* __restrict__ dst,
    float* __restrict__ h,
    int n_edges)
{
    int gid  = blockIdx.x * blockDim.x + threadIdx.x;
    int edge = gid >> 6;
    int lane = threadIdx.x & 63;
    if (edge >= n_edges) return;

    int s = src[edge];
    int d = dst[edge];

    const float2* frow = (const float2*)(feature + (size_t)s * 128);
    float2 v = frow[lane];

    float* hrow = h + (size_t)d * 128;
    atomicAdd(hrow + 2 * lane,     v.x);
    atomicAdd(hrow + 2 * lane + 1, v.y);
}

// Phase 3: out[n,o] = sum_d h[n,d] * W[o,d] + b[o].
// Block = 256 threads handles 16 rows. W staged in LDS in two 64-col halves
// (stride 68 floats == 4 mod 32 -> conflict-free float4 lane access).
// h rows staged in LDS (stride 132), read as wave-broadcast float4.
// Each thread: one output column o = tid&127, 8 rows (half = tid>>7).
#define HS_STRIDE 132
#define WS_STRIDE 68

__global__ __launch_bounds__(256, 2) void gcn_linear_kernel(
    const float* __restrict__ h,
    const float* __restrict__ W,
    const float* __restrict__ b,
    float* __restrict__ out,
    int n_nodes)
{
    __shared__ float Ws[128 * WS_STRIDE];
    __shared__ float hs[16][HS_STRIDE];

    int tid  = threadIdx.x;
    int row0 = blockIdx.x * 16;

    // Stage the 16 h rows (full 128 cols) once.
    for (int i = tid; i < 16 * 32; i += 256) {
        int r  = i >> 5;
        int dd = (i & 31) << 2;
        float4 v;
        if (row0 + r < n_nodes)
            v = *(const float4*)(h + (size_t)(row0 + r) * 128 + dd);
        else
            v = make_float4(0.f, 0.f, 0.f, 0.f);
        *(float4*)(&hs[r][dd]) = v;
    }

    int o    = tid & 127;
    int half = tid >> 7;

    float acc[8];
#pragma unroll
    for (int r = 0; r < 8; r++) acc[r] = 0.f;

    for (int kk = 0; kk < 128; kk += 64) {
        __syncthreads();  // protect Ws from previous half still being read
        // Stage W[:, kk:kk+64]: 128 rows x 16 float4.
        for (int i = tid; i < 128 * 16; i += 256) {
            int oo = i >> 4;
            int dd = (i & 15) << 2;
            float4 w = *(const float4*)(W + (size_t)oo * 128 + kk + dd);
            *(float4*)(Ws + oo * WS_STRIDE + dd) = w;
        }
        __syncthreads();

        for (int dd = 0; dd < 64; dd += 4) {
            float4 w = *(const float4*)(Ws + o * WS_STRIDE + dd);
#pragma unroll
            for (int r = 0; r < 8; r++) {
                float4 hv = *(const float4*)(&hs[half * 8 + r][kk + dd]);
                acc[r] += w.x * hv.x + w.y * hv.y + w.z * hv.z + w.w * hv.w;
            }
        }
    }

    float bias = b[o];
#pragma unroll
    for (int r = 0; r < 8; r++) {
        int row = row0 + half * 8 + r;
        if (row < n_nodes)
            out[(size_t)row * 128 + o] = acc[r] + bias;
    }
}

extern "C" void kernel_launch(void* const* d_in, const int* in_sizes, int n_in,
                              void* d_out, int out_size, void* d_ws, size_t ws_size,
                              hipStream_t stream) {
    const float* feature = (const float*)d_in[0];
    const int*   src     = (const int*)d_in[1];
    const int*   dst     = (const int*)d_in[2];
    const float* W       = (const float*)d_in[3];
    const float* b       = (const float*)d_in[4];
    float*       out     = (float*)d_out;

    const int D  = 128;
    int n_nodes  = in_sizes[0] / D;
    int n_edges  = in_sizes[1];

    float* h = (float*)d_ws;  // 50000*128*4 = 25.6 MB scratch

    // Phase 1: zero the accumulator (d_ws is poisoned 0xAA every call).
    hipMemsetAsync(h, 0, (size_t)n_nodes * D * sizeof(float), stream);

    // Phase 2: scatter-add. One 64-lane wave per edge; 4 edges per 256-block.
    {
        long long total_threads = (long long)n_edges * 64;
        int blocks = (int)((total_threads + 255) / 256);
        gcn_scatter_kernel<<<blocks, 256, 0, stream>>>(feature, src, dst, h, n_edges);
    }

    // Phase 3: linear projection. 16 rows per 256-thread block.
    {
        int blocks = (n_nodes + 15) / 16;
        gcn_linear_kernel<<<blocks, 256, 0, stream>>>(h, W, b, out, n_nodes);
    }
}

// Round 2
// 323.175 us; speedup vs baseline: 2.4643x; 2.4643x over previous
//
#include <hip/hip_runtime.h>
#include <hip/hip_bf16.h>

// ---------------------------------------------------------------------------
// Phase A: counting sort of edges by dst -> CSR (offsets + src_sorted).
// Phase B: per-node gather-accumulate (no atomics on the 128-wide payload).
// Phase C: linear projection out = h @ W^T + b (in place over h in d_out).
// ---------------------------------------------------------------------------

// A1: histogram of dst into cnt[] (cnt pre-zeroed by hipMemsetAsync).
__global__ __launch_bounds__(256) void gcn_hist_kernel(
    const int* __restrict__ dst, int* __restrict__ cnt, int n_edges)
{
    int e = blockIdx.x * blockDim.x + threadIdx.x;
    if (e < n_edges) atomicAdd(&cnt[dst[e]], 1);
}

// A2: exclusive scan of cnt[0..n) -> offs[0..n]; also rewrite cnt[i] = offs[i]
// so cnt doubles as the scatter cursor. Single block, 1024 threads,
// shfl-based wave scan + 16-wave LDS combine.
__global__ __launch_bounds__(1024) void gcn_scan_kernel(
    int* __restrict__ cnt, int* __restrict__ offs, int n)
{
    __shared__ int wsum[16];
    int tid  = threadIdx.x;
    int lane = tid & 63;
    int wid  = tid >> 6;
    int running = 0;

    for (int base = 0; base < n; base += 1024) {
        int i    = base + tid;
        int orig = (i < n) ? cnt[i] : 0;
        int x    = orig;
        // wave-inclusive scan
        #pragma unroll
        for (int off = 1; off < 64; off <<= 1) {
            int y = __shfl_up(x, off, 64);
            if (lane >= off) x += y;
        }
        if (lane == 63) wsum[wid] = x;
        __syncthreads();
        if (wid == 0) {
            int w = (lane < 16) ? wsum[lane] : 0;
            #pragma unroll
            for (int off = 1; off < 16; off <<= 1) {
                int y = __shfl_up(w, off, 64);
                if (lane >= off) w += y;
            }
            if (lane < 16) wsum[lane] = w;  // inclusive scan of wave sums
        }
        __syncthreads();
        int wexcl = (wid == 0) ? 0 : wsum[wid - 1];
        int excl  = running + wexcl + (x - orig);
        if (i < n) { offs[i] = excl; cnt[i] = excl; }
        running += wsum[15];      // chunk total, uniform across threads
        __syncthreads();          // protect wsum before next chunk
    }
    if (tid == 0) offs[n] = running;
}

// A3: scatter edge src ids into CSR order. cnt[] is the cursor (== offsets).
__global__ __launch_bounds__(256) void gcn_scatter_idx_kernel(
    const int* __restrict__ src, const int* __restrict__ dst,
    int* __restrict__ cursor, int* __restrict__ src_sorted, int n_edges)
{
    int e = blockIdx.x * blockDim.x + threadIdx.x;
    if (e < n_edges) {
        int pos = atomicAdd(&cursor[dst[e]], 1);
        src_sorted[pos] = src[e];
    }
}

// B: one wave per node. Walk the CSR segment, accumulate float2/lane in
// registers, write the h row once. Degree-0 nodes write zeros (so no memset
// of h is needed).
__global__ __launch_bounds__(256) void gcn_gather_kernel(
    const float* __restrict__ feature,
    const int* __restrict__ offs,
    const int* __restrict__ src_sorted,
    float* __restrict__ h,
    int n_nodes)
{
    int gid  = blockIdx.x * blockDim.x + threadIdx.x;
    int node = gid >> 6;
    int lane = threadIdx.x & 63;
    if (node >= n_nodes) return;

    int beg = offs[node];
    int end = offs[node + 1];

    float2 acc = make_float2(0.f, 0.f);
    int i = beg;
    // unroll-by-2 for memory-level parallelism
    for (; i + 1 < end; i += 2) {
        int s0 = src_sorted[i];
        int s1 = src_sorted[i + 1];
        float2 v0 = ((const float2*)(feature + (size_t)s0 * 128))[lane];
        float2 v1 = ((const float2*)(feature + (size_t)s1 * 128))[lane];
        acc.x += v0.x + v1.x;
        acc.y += v0.y + v1.y;
    }
    if (i < end) {
        int s = src_sorted[i];
        float2 v = ((const float2*)(feature + (size_t)s * 128))[lane];
        acc.x += v.x;
        acc.y += v.y;
    }
    ((float2*)(h + (size_t)node * 128))[lane] = acc;
}

// C: out[n,o] = sum_d h[n,d] * W[o,d] + b[o]. In-place over h (= d_out):
// each block stages its 16 h rows into LDS (sync) before any write-back.
#define HS_STRIDE 132
#define WS_STRIDE 68

__global__ __launch_bounds__(256, 2) void gcn_linear_kernel(
    const float* __restrict__ h,
    const float* __restrict__ W,
    const float* __restrict__ b,
    float* __restrict__ out,
    int n_nodes)
{
    __shared__ float Ws[128 * WS_STRIDE];
    __shared__ float hs[16][HS_STRIDE];

    int tid  = threadIdx.x;
    int row0 = blockIdx.x * 16;

    for (int i = tid; i < 16 * 32; i += 256) {
        int r  = i >> 5;
        int dd = (i & 31) << 2;
        float4 v;
        if (row0 + r < n_nodes)
            v = *(const float4*)(h + (size_t)(row0 + r) * 128 + dd);
        else
            v = make_float4(0.f, 0.f, 0.f, 0.f);
        *(float4*)(&hs[r][dd]) = v;
    }

    int o    = tid & 127;
    int half = tid >> 7;

    float acc[8];
#pragma unroll
    for (int r = 0; r < 8; r++) acc[r] = 0.f;

    for (int kk = 0; kk < 128; kk += 64) {
        __syncthreads();  // covers hs staging (1st iter) + Ws reuse (2nd iter)
        for (int i = tid; i < 128 * 16; i += 256) {
            int oo = i >> 4;
            int dd = (i & 15) << 2;
            float4 w = *(const float4*)(W + (size_t)oo * 128 + kk + dd);
            *(float4*)(Ws + oo * WS_STRIDE + dd) = w;
        }
        __syncthreads();

        for (int dd = 0; dd < 64; dd += 4) {
            float4 w = *(const float4*)(Ws + o * WS_STRIDE + dd);
#pragma unroll
            for (int r = 0; r < 8; r++) {
                float4 hv = *(const float4*)(&hs[half * 8 + r][kk + dd]);
                acc[r] += w.x * hv.x + w.y * hv.y + w.z * hv.z + w.w * hv.w;
            }
        }
    }

    float bias = b[o];
#pragma unroll
    for (int r = 0; r < 8; r++) {
        int row = row0 + half * 8 + r;
        if (row < n_nodes)
            out[(size_t)row * 128 + o] = acc[r] + bias;
    }
}

extern "C" void kernel_launch(void* const* d_in, const int* in_sizes, int n_in,
                              void* d_out, int out_size, void* d_ws, size_t ws_size,
                              hipStream_t stream) {
    const float* feature = (const float*)d_in[0];
    const int*   src     = (const int*)d_in[1];
    const int*   dst     = (const int*)d_in[2];
    const float* W       = (const float*)d_in[3];
    const float* b       = (const float*)d_in[4];

    const int D  = 128;
    int n_nodes  = in_sizes[0] / D;
    int n_edges  = in_sizes[1];

    // h lives in d_out: gather fully writes it, linear transforms it in place.
    float* h   = (float*)d_out;
    float* out = (float*)d_out;

    // Workspace: cnt/cursor [N] | offs [N+1] | src_sorted [E]  (~3.6 MB)
    int* cnt        = (int*)d_ws;
    int* offs       = cnt + n_nodes;
    int* src_sorted = offs + (n_nodes + 1);

    hipMemsetAsync(cnt, 0, (size_t)n_nodes * sizeof(int), stream);

    {
        int blocks = (n_edges + 255) / 256;
        gcn_hist_kernel<<<blocks, 256, 0, stream>>>(dst, cnt, n_edges);
    }

    gcn_scan_kernel<<<1, 1024, 0, stream>>>(cnt, offs, n_nodes);

    {
        int blocks = (n_edges + 255) / 256;
        gcn_scatter_idx_kernel<<<blocks, 256, 0, stream>>>(src, dst, cnt, src_sorted, n_edges);
    }

    {
        long long total_threads = (long long)n_nodes * 64;
        int blocks = (int)((total_threads + 255) / 256);
        gcn_gather_kernel<<<blocks, 256, 0, stream>>>(feature, offs, src_sorted, h, n_nodes);
    }

    {
        int blocks = (n_nodes + 15) / 16;
        gcn_linear_kernel<<<blocks, 256, 0, stream>>>(h, W, b, out, n_nodes);
    }
}

// Round 4
// 270.814 us; speedup vs baseline: 2.9408x; 1.1933x over previous
//
#include <hip/hip_runtime.h>
#include <hip/hip_bf16.h>

// ---------------------------------------------------------------------------
// A: counting sort of edges by dst -> CSR   (hist, scan x3, scatter_idx)
// B: per-node gather-accumulate (no atomics on the 128-wide payload)
// C: linear projection out = h @ W^T + b, register-tiled 8x4 per thread
// ---------------------------------------------------------------------------

// A1: histogram of dst into cnt[] (cnt pre-zeroed). 4 edges/thread, int4.
__global__ __launch_bounds__(256) void gcn_hist_kernel(
    const int* __restrict__ dst, int* __restrict__ cnt, int n_edges)
{
    int e4 = (blockIdx.x * blockDim.x + threadIdx.x) * 4;
    if (e4 + 3 < n_edges) {
        int4 d = *(const int4*)(dst + e4);
        atomicAdd(&cnt[d.x], 1);
        atomicAdd(&cnt[d.y], 1);
        atomicAdd(&cnt[d.z], 1);
        atomicAdd(&cnt[d.w], 1);
    } else {
        for (int e = e4; e < n_edges; ++e) atomicAdd(&cnt[dst[e]], 1);
    }
}

// A2a: per-block (1024-elem) exclusive scan; block totals to blk_sums.
__global__ __launch_bounds__(1024) void gcn_scan1_kernel(
    const int* __restrict__ cnt, int* __restrict__ offs,
    int* __restrict__ blk_sums, int n)
{
    __shared__ int wsum[16];
    int tid  = threadIdx.x;
    int lane = tid & 63;
    int wid  = tid >> 6;
    int i    = blockIdx.x * 1024 + tid;

    int orig = (i < n) ? cnt[i] : 0;
    int x    = orig;
    #pragma unroll
    for (int off = 1; off < 64; off <<= 1) {
        int y = __shfl_up(x, off, 64);
        if (lane >= off) x += y;
    }
    if (lane == 63) wsum[wid] = x;
    __syncthreads();
    if (wid == 0) {
        int w = (lane < 16) ? wsum[lane] : 0;
        #pragma unroll
        for (int off = 1; off < 16; off <<= 1) {
            int y = __shfl_up(w, off, 64);
            if (lane >= off) w += y;
        }
        if (lane < 16) wsum[lane] = w;
    }
    __syncthreads();
    int wexcl = (wid == 0) ? 0 : wsum[wid - 1];
    if (i < n) offs[i] = wexcl + (x - orig);        // block-local exclusive
    // SINGLE writer for the block total (was a two-wave race in round 3).
    if (tid == 0) blk_sums[blockIdx.x] = wsum[15];
}

// A2b: exclusive scan of block sums (nblk <= 64), one wave.
__global__ __launch_bounds__(64) void gcn_scan2_kernel(
    int* __restrict__ blk_sums, int* __restrict__ blk_off, int nblk)
{
    int lane = threadIdx.x;
    int orig = (lane < nblk) ? blk_sums[lane] : 0;
    int x    = orig;
    #pragma unroll
    for (int off = 1; off < 64; off <<= 1) {
        int y = __shfl_up(x, off, 64);
        if (lane >= off) x += y;
    }
    if (lane < nblk) blk_off[lane] = x - orig;
    if (lane == 63) blk_off[nblk] = x;   // grand total
}

// A2c: add block offsets; write cursor copy and offs[n].
__global__ __launch_bounds__(1024) void gcn_scan3_kernel(
    int* __restrict__ offs, int* __restrict__ cursor,
    const int* __restrict__ blk_off, int n, int nblk)
{
    int i = blockIdx.x * 1024 + threadIdx.x;
    if (i < n) {
        int v = offs[i] + blk_off[blockIdx.x];
        offs[i]   = v;
        cursor[i] = v;
    }
    if (i == 0) offs[n] = blk_off[nblk];
}

// A3: scatter edge src ids into CSR order. 4 edges/thread.
__global__ __launch_bounds__(256) void gcn_scatter_idx_kernel(
    const int* __restrict__ src, const int* __restrict__ dst,
    int* __restrict__ cursor, int* __restrict__ src_sorted, int n_edges)
{
    int e4 = (blockIdx.x * blockDim.x + threadIdx.x) * 4;
    if (e4 + 3 < n_edges) {
        int4 d = *(const int4*)(dst + e4);
        int4 s = *(const int4*)(src + e4);
        src_sorted[atomicAdd(&cursor[d.x], 1)] = s.x;
        src_sorted[atomicAdd(&cursor[d.y], 1)] = s.y;
        src_sorted[atomicAdd(&cursor[d.z], 1)] = s.z;
        src_sorted[atomicAdd(&cursor[d.w], 1)] = s.w;
    } else {
        for (int e = e4; e < n_edges; ++e)
            src_sorted[atomicAdd(&cursor[dst[e]], 1)] = src[e];
    }
}

// B: one wave per node; accumulate float2/lane, write h row once.
__global__ __launch_bounds__(256) void gcn_gather_kernel(
    const float* __restrict__ feature,
    const int* __restrict__ offs,
    const int* __restrict__ src_sorted,
    float* __restrict__ h,
    int n_nodes)
{
    int gid  = blockIdx.x * blockDim.x + threadIdx.x;
    int node = gid >> 6;
    int lane = threadIdx.x & 63;
    if (node >= n_nodes) return;

    int beg = offs[node];
    int end = offs[node + 1];

    float2 acc = make_float2(0.f, 0.f);
    int i = beg;
    for (; i + 3 < end; i += 4) {   // 4 rows in flight for latency hiding
        int s0 = src_sorted[i];
        int s1 = src_sorted[i + 1];
        int s2 = src_sorted[i + 2];
        int s3 = src_sorted[i + 3];
        float2 v0 = ((const float2*)(feature + (size_t)s0 * 128))[lane];
        float2 v1 = ((const float2*)(feature + (size_t)s1 * 128))[lane];
        float2 v2 = ((const float2*)(feature + (size_t)s2 * 128))[lane];
        float2 v3 = ((const float2*)(feature + (size_t)s3 * 128))[lane];
        acc.x += (v0.x + v1.x) + (v2.x + v3.x);
        acc.y += (v0.y + v1.y) + (v2.y + v3.y);
    }
    for (; i < end; ++i) {
        int s = src_sorted[i];
        float2 v = ((const float2*)(feature + (size_t)s * 128))[lane];
        acc.x += v.x;
        acc.y += v.y;
    }
    ((float2*)(h + (size_t)node * 128))[lane] = acc;
}

// C: out[n,o] = sum_d h[n,d] * W[o,d] + b[o], in place over h (= d_out).
// Block tile: 64 rows x 128 cols. Thread (o-group = tid&31, r-group = tid>>5)
// owns acc[8 rows][4 cols]. W staged per 64-k half with row stride 65
// (lane stride 4*65 dwords == 4 mod 32 banks -> conflict-free b128).
// h rows staged full-k, stride 128 (reads are wave-broadcast).
#define WS2_STRIDE 65

__global__ __launch_bounds__(256, 2) void gcn_linear_kernel(
    const float* __restrict__ h,
    const float* __restrict__ W,
    const float* __restrict__ b,
    float* __restrict__ out,
    int n_nodes)
{
    __shared__ float hs[64 * 128];            // 32 KB
    __shared__ float Ws[128 * WS2_STRIDE];    // 33.3 KB

    int tid  = threadIdx.x;
    int row0 = blockIdx.x * 64;

    // Stage 64 h rows (full 128 cols): 2048 float4 by 256 threads.
    for (int i = tid; i < 64 * 32; i += 256) {
        int r  = i >> 5;
        int dd = (i & 31) << 2;
        float4 v;
        if (row0 + r < n_nodes)
            v = *(const float4*)(h + (size_t)(row0 + r) * 128 + dd);
        else
            v = make_float4(0.f, 0.f, 0.f, 0.f);
        *(float4*)(&hs[r * 128 + dd]) = v;
    }

    int o0 = (tid & 31) << 2;   // 4 output cols
    int r0 = (tid >> 5) << 3;   // 8 rows

    float acc[8][4];
    #pragma unroll
    for (int i = 0; i < 8; i++)
        #pragma unroll
        for (int j = 0; j < 4; j++) acc[i][j] = 0.f;

    for (int kk = 0; kk < 128; kk += 64) {
        __syncthreads();  // covers hs staging (1st iter) + Ws reuse (2nd iter)
        // Stage W[:, kk:kk+64]: 128 rows x 16 float4.
        for (int i = tid; i < 128 * 16; i += 256) {
            int oo = i >> 4;
            int dd = (i & 15) << 2;
            float4 w = *(const float4*)(W + (size_t)oo * 128 + kk + dd);
            *(float4*)(&Ws[oo * WS2_STRIDE + dd]) = w;
        }
        __syncthreads();

        #pragma unroll 2
        for (int k4 = 0; k4 < 64; k4 += 4) {
            float4 wv[4];
            #pragma unroll
            for (int j = 0; j < 4; j++)
                wv[j] = *(const float4*)(&Ws[(o0 + j) * WS2_STRIDE + k4]);
            #pragma unroll
            for (int i = 0; i < 8; i++) {
                float4 hv = *(const float4*)(&hs[(r0 + i) * 128 + kk + k4]);
                #pragma unroll
                for (int j = 0; j < 4; j++) {
                    acc[i][j] += hv.x * wv[j].x + hv.y * wv[j].y
                               + hv.z * wv[j].z + hv.w * wv[j].w;
                }
            }
        }
    }

    float4 bias = *(const float4*)(b + o0);
    #pragma unroll
    for (int i = 0; i < 8; i++) {
        int row = row0 + r0 + i;
        if (row < n_nodes) {
            float4 v = make_float4(acc[i][0] + bias.x, acc[i][1] + bias.y,
                                   acc[i][2] + bias.z, acc[i][3] + bias.w);
            *(float4*)(out + (size_t)row * 128 + o0) = v;
        }
    }
}

extern "C" void kernel_launch(void* const* d_in, const int* in_sizes, int n_in,
                              void* d_out, int out_size, void* d_ws, size_t ws_size,
                              hipStream_t stream) {
    const float* feature = (const float*)d_in[0];
    const int*   src     = (const int*)d_in[1];
    const int*   dst     = (const int*)d_in[2];
    const float* W       = (const float*)d_in[3];
    const float* b       = (const float*)d_in[4];

    const int D  = 128;
    int n_nodes  = in_sizes[0] / D;
    int n_edges  = in_sizes[1];

    float* h   = (float*)d_out;   // gather fully writes; linear is in-place
    float* out = (float*)d_out;

    // Workspace layout (ints): cnt/cursor[N] | offs[N+1] | src_sorted[E] |
    //                          blk_sums[64+1] | blk_off[64+1]
    int* cnt        = (int*)d_ws;
    int* offs       = cnt + n_nodes;
    int* src_sorted = offs + (n_nodes + 1);
    int* blk_sums   = src_sorted + n_edges;
    int* blk_off    = blk_sums + 65;

    int nblk = (n_nodes + 1023) / 1024;   // 49 for N=50000 (fits one wave)

    hipMemsetAsync(cnt, 0, (size_t)n_nodes * sizeof(int), stream);

    {
        int threads = (n_edges + 3) / 4;
        gcn_hist_kernel<<<(threads + 255) / 256, 256, 0, stream>>>(dst, cnt, n_edges);
    }

    gcn_scan1_kernel<<<nblk, 1024, 0, stream>>>(cnt, offs, blk_sums, n_nodes);
    gcn_scan2_kernel<<<1, 64, 0, stream>>>(blk_sums, blk_off, nblk);
    gcn_scan3_kernel<<<nblk, 1024, 0, stream>>>(offs, cnt, blk_off, n_nodes, nblk);

    {
        int threads = (n_edges + 3) / 4;
        gcn_scatter_idx_kernel<<<(threads + 255) / 256, 256, 0, stream>>>(
            src, dst, cnt, src_sorted, n_edges);
    }

    {
        long long total_threads = (long long)n_nodes * 64;
        int blocks = (int)((total_threads + 255) / 256);
        gcn_gather_kernel<<<blocks, 256, 0, stream>>>(feature, offs, src_sorted, h, n_nodes);
    }

    {
        int blocks = (n_nodes + 63) / 64;
        gcn_linear_kernel<<<blocks, 256, 0, stream>>>(h, W, b, out, n_nodes);
    }
}

// Round 5
// 219.410 us; speedup vs baseline: 3.6298x; 1.2343x over previous
//
#include <hip/hip_runtime.h>
#include <hip/hip_bf16.h>

// ---------------------------------------------------------------------------
// CSR build (two-level, write-locality-friendly):
//   p_hist      : LDS histogram of coarse buckets (node>>7), 1 atomic/(blk,bkt)
//   p_scan      : single-wave exclusive scan of bucket counts
//   p_scatter   : partition (dst,src) pairs into bucket regions (dense runs)
//   local_csr   : per-bucket exact CSR (LDS hist+scan), coalesced offs,
//                 src_sorted writes confined to the block's own region
// B: gcn_gather : one wave per node, register accumulate, single row write
// C: gcn_linear : register-tiled 8x4 fp32 GEMM, in place over h (= d_out)
// ---------------------------------------------------------------------------

#define BKT_SHIFT 7                 // 128 nodes per bucket
#define MAX_BKT   512               // >= ceil(50000/128)+1 = 392

// --- p_hist: per-block LDS histogram of dst buckets -> global bucket_cnt ---
__global__ __launch_bounds__(256) void p_hist_kernel(
    const int* __restrict__ dst, int* __restrict__ bucket_cnt,
    int n_edges, int nb, int chunk)
{
    __shared__ int lcnt[MAX_BKT];
    int tid = threadIdx.x;
    int e0  = blockIdx.x * chunk;
    int e1  = min(e0 + chunk, n_edges);

    for (int i = tid; i < nb; i += 256) lcnt[i] = 0;
    __syncthreads();
    for (int e = e0 + tid; e < e1; e += 256)
        atomicAdd(&lcnt[dst[e] >> BKT_SHIFT], 1);
    __syncthreads();
    for (int i = tid; i < nb; i += 256) {
        int c = lcnt[i];
        if (c) atomicAdd(&bucket_cnt[i], c);
    }
}

// --- p_scan: one wave, 8 buckets/lane; writes bucket_off[0..nb] + cursor ---
__global__ __launch_bounds__(64) void p_scan_kernel(
    const int* __restrict__ bucket_cnt, int* __restrict__ bucket_off,
    int* __restrict__ bucket_cursor, int nb)
{
    int lane = threadIdx.x;
    const int PER = 8;              // 64*8 = 512 >= nb+1
    int base = lane * PER;
    int v[PER];
    int sum = 0;
    #pragma unroll
    for (int j = 0; j < PER; j++) {
        v[j] = (base + j < nb) ? bucket_cnt[base + j] : 0;
        sum += v[j];
    }
    int x = sum;
    #pragma unroll
    for (int off = 1; off < 64; off <<= 1) {
        int y = __shfl_up(x, off, 64);
        if (lane >= off) x += y;
    }
    int run = x - sum;              // exclusive prefix of this lane's range
    #pragma unroll
    for (int j = 0; j < PER; j++) {
        int idx = base + j;
        if (idx <= nb) {
            bucket_off[idx] = run;
            if (idx < nb) bucket_cursor[idx] = run;
        }
        run += v[j];
    }
}

// --- p_scatter: partition edges into bucket regions as (dst,src) pairs ---
__global__ __launch_bounds__(256) void p_scatter_kernel(
    const int* __restrict__ src, const int* __restrict__ dst,
    int* __restrict__ bucket_cursor, int2* __restrict__ pairs,
    int n_edges, int nb, int chunk)
{
    __shared__ int lcnt[MAX_BKT];
    __shared__ int lcur[MAX_BKT];
    int tid = threadIdx.x;
    int e0  = blockIdx.x * chunk;
    int e1  = min(e0 + chunk, n_edges);

    for (int i = tid; i < nb; i += 256) lcnt[i] = 0;
    __syncthreads();
    for (int e = e0 + tid; e < e1; e += 256)
        atomicAdd(&lcnt[dst[e] >> BKT_SHIFT], 1);
    __syncthreads();
    // reserve a contiguous run per bucket for this block
    for (int i = tid; i < nb; i += 256) {
        int c = lcnt[i];
        lcur[i] = c ? atomicAdd(&bucket_cursor[i], c) : 0;
    }
    __syncthreads();
    for (int e = e0 + tid; e < e1; e += 256) {
        int d = dst[e];
        int s = src[e];
        int pos = atomicAdd(&lcur[d >> BKT_SHIFT], 1);
        pairs[pos] = make_int2(d, s);
    }
}

// --- local_csr: per bucket (128 nodes) exact CSR via LDS hist + scan ---
__global__ __launch_bounds__(256) void local_csr_kernel(
    const int2* __restrict__ pairs, const int* __restrict__ bucket_off,
    int* __restrict__ offs, int* __restrict__ src_sorted,
    int n_nodes, int n_edges)
{
    __shared__ int hist[128];
    __shared__ int excl[128];
    __shared__ int curs[128];
    int b   = blockIdx.x;
    int tid = threadIdx.x;
    int node_base = b << BKT_SHIFT;
    int bstart = bucket_off[b];
    int bend   = bucket_off[b + 1];

    if (tid < 128) hist[tid] = 0;
    __syncthreads();
    for (int i = bstart + tid; i < bend; i += 256)
        atomicAdd(&hist[pairs[i].x - node_base], 1);
    __syncthreads();
    if (tid < 64) {   // wave 0: exclusive scan of 128 values, 2 per lane
        int v0 = hist[2 * tid];
        int v1 = hist[2 * tid + 1];
        int s  = v0 + v1;
        int x  = s;
        #pragma unroll
        for (int off = 1; off < 64; off <<= 1) {
            int y = __shfl_up(x, off, 64);
            if (tid >= off) x += y;
        }
        int e0 = x - s;
        excl[2 * tid]     = e0;
        excl[2 * tid + 1] = e0 + v0;
    }
    __syncthreads();
    if (tid < 128) {
        int pos = bstart + excl[tid];
        int node = node_base + tid;
        if (node < n_nodes) offs[node] = pos;
        curs[tid] = pos;
    }
    __syncthreads();
    for (int i = bstart + tid; i < bend; i += 256) {
        int2 p = pairs[i];
        int pos = atomicAdd(&curs[p.x - node_base], 1);
        src_sorted[pos] = p.y;
    }
    if (b == 0 && tid == 0) offs[n_nodes] = n_edges;
}

// --- B: one wave per node; accumulate float2/lane, write h row once ---
__global__ __launch_bounds__(256) void gcn_gather_kernel(
    const float* __restrict__ feature,
    const int* __restrict__ offs,
    const int* __restrict__ src_sorted,
    float* __restrict__ h,
    int n_nodes)
{
    int gid  = blockIdx.x * blockDim.x + threadIdx.x;
    int node = gid >> 6;
    int lane = threadIdx.x & 63;
    if (node >= n_nodes) return;

    int beg = offs[node];
    int end = offs[node + 1];

    float2 acc = make_float2(0.f, 0.f);
    int i = beg;
    for (; i + 3 < end; i += 4) {   // 4 rows in flight for latency hiding
        int s0 = src_sorted[i];
        int s1 = src_sorted[i + 1];
        int s2 = src_sorted[i + 2];
        int s3 = src_sorted[i + 3];
        float2 v0 = ((const float2*)(feature + (size_t)s0 * 128))[lane];
        float2 v1 = ((const float2*)(feature + (size_t)s1 * 128))[lane];
        float2 v2 = ((const float2*)(feature + (size_t)s2 * 128))[lane];
        float2 v3 = ((const float2*)(feature + (size_t)s3 * 128))[lane];
        acc.x += (v0.x + v1.x) + (v2.x + v3.x);
        acc.y += (v0.y + v1.y) + (v2.y + v3.y);
    }
    for (; i < end; ++i) {
        int s = src_sorted[i];
        float2 v = ((const float2*)(feature + (size_t)s * 128))[lane];
        acc.x += v.x;
        acc.y += v.y;
    }
    ((float2*)(h + (size_t)node * 128))[lane] = acc;
}

// --- C: out = h @ W^T + b, register-tiled 8 rows x 4 cols per thread ---
#define WS2_STRIDE 65

__global__ __launch_bounds__(256, 2) void gcn_linear_kernel(
    const float* __restrict__ h,
    const float* __restrict__ W,
    const float* __restrict__ b,
    float* __restrict__ out,
    int n_nodes)
{
    __shared__ float hs[64 * 128];            // 32 KB
    __shared__ float Ws[128 * WS2_STRIDE];    // 33.3 KB

    int tid  = threadIdx.x;
    int row0 = blockIdx.x * 64;

    for (int i = tid; i < 64 * 32; i += 256) {
        int r  = i >> 5;
        int dd = (i & 31) << 2;
        float4 v;
        if (row0 + r < n_nodes)
            v = *(const float4*)(h + (size_t)(row0 + r) * 128 + dd);
        else
            v = make_float4(0.f, 0.f, 0.f, 0.f);
        *(float4*)(&hs[r * 128 + dd]) = v;
    }

    int o0 = (tid & 31) << 2;   // 4 output cols
    int r0 = (tid >> 5) << 3;   // 8 rows

    float acc[8][4];
    #pragma unroll
    for (int i = 0; i < 8; i++)
        #pragma unroll
        for (int j = 0; j < 4; j++) acc[i][j] = 0.f;

    for (int kk = 0; kk < 128; kk += 64) {
        __syncthreads();  // covers hs staging (1st iter) + Ws reuse (2nd iter)
        for (int i = tid; i < 128 * 16; i += 256) {
            int oo = i >> 4;
            int dd = (i & 15) << 2;
            float4 w = *(const float4*)(W + (size_t)oo * 128 + kk + dd);
            *(float4*)(&Ws[oo * WS2_STRIDE + dd]) = w;
        }
        __syncthreads();

        #pragma unroll 2
        for (int k4 = 0; k4 < 64; k4 += 4) {
            float4 wv[4];
            #pragma unroll
            for (int j = 0; j < 4; j++)
                wv[j] = *(const float4*)(&Ws[(o0 + j) * WS2_STRIDE + k4]);
            #pragma unroll
            for (int i = 0; i < 8; i++) {
                float4 hv = *(const float4*)(&hs[(r0 + i) * 128 + kk + k4]);
                #pragma unroll
                for (int j = 0; j < 4; j++) {
                    acc[i][j] += hv.x * wv[j].x + hv.y * wv[j].y
                               + hv.z * wv[j].z + hv.w * wv[j].w;
                }
            }
        }
    }

    float4 bias = *(const float4*)(b + o0);
    #pragma unroll
    for (int i = 0; i < 8; i++) {
        int row = row0 + r0 + i;
        if (row < n_nodes) {
            float4 v = make_float4(acc[i][0] + bias.x, acc[i][1] + bias.y,
                                   acc[i][2] + bias.z, acc[i][3] + bias.w);
            *(float4*)(out + (size_t)row * 128 + o0) = v;
        }
    }
}

extern "C" void kernel_launch(void* const* d_in, const int* in_sizes, int n_in,
                              void* d_out, int out_size, void* d_ws, size_t ws_size,
                              hipStream_t stream) {
    const float* feature = (const float*)d_in[0];
    const int*   src     = (const int*)d_in[1];
    const int*   dst     = (const int*)d_in[2];
    const float* W       = (const float*)d_in[3];
    const float* b       = (const float*)d_in[4];

    const int D  = 128;
    int n_nodes  = in_sizes[0] / D;
    int n_edges  = in_sizes[1];
    int nb       = (n_nodes + 127) >> BKT_SHIFT;   // 391 coarse buckets

    float* h   = (float*)d_out;   // gather fully writes; linear is in-place
    float* out = (float*)d_out;

    // Workspace (pairs first for 8B alignment):
    // pairs[E] int2 | src_sorted[E] | offs[N+1] | bucket_cnt[512] |
    // bucket_off[513] | bucket_cursor[512]        (~9.8 MB)
    int2* pairs        = (int2*)d_ws;
    int* src_sorted    = (int*)(pairs + n_edges);
    int* offs          = src_sorted + n_edges;
    int* bucket_cnt    = offs + (n_nodes + 1);
    int* bucket_off    = bucket_cnt + MAX_BKT;
    int* bucket_cursor = bucket_off + (MAX_BKT + 1);

    hipMemsetAsync(bucket_cnt, 0, (size_t)nb * sizeof(int), stream);

    const int NPART = 128;                      // partition blocks
    int chunk = (n_edges + NPART - 1) / NPART;  // 6250 edges/block

    p_hist_kernel<<<NPART, 256, 0, stream>>>(dst, bucket_cnt, n_edges, nb, chunk);
    p_scan_kernel<<<1, 64, 0, stream>>>(bucket_cnt, bucket_off, bucket_cursor, nb);
    p_scatter_kernel<<<NPART, 256, 0, stream>>>(src, dst, bucket_cursor, pairs,
                                                n_edges, nb, chunk);
    local_csr_kernel<<<nb, 256, 0, stream>>>(pairs, bucket_off, offs, src_sorted,
                                             n_nodes, n_edges);

    {
        long long total_threads = (long long)n_nodes * 64;
        int blocks = (int)((total_threads + 255) / 256);
        gcn_gather_kernel<<<blocks, 256, 0, stream>>>(feature, offs, src_sorted, h, n_nodes);
    }

    {
        int blocks = (n_nodes + 63) / 64;
        gcn_linear_kernel<<<blocks, 256, 0, stream>>>(h, W, b, out, n_nodes);
    }
}

// Round 6
// 206.406 us; speedup vs baseline: 3.8584x; 1.0630x over previous
//
#include <hip/hip_runtime.h>
#include <hip/hip_bf16.h>

// ---------------------------------------------------------------------------
// conv_bf16   : feature (+W) fp32 -> bf16 (RNE), one flat pass
// CSR build (two-level, round-5 proven):
//   p_hist / p_scan / p_scatter / local_csr
// gather_mm   : FUSED per-64-node block: wave gathers its 16 rows (bf16
//               accum fp32) into padded LDS tile, then MFMA 16x16x32_bf16
//               against W_bf, bias-add, fp32 store. No h round-trip.
// ---------------------------------------------------------------------------

#define BKT_SHIFT 7                 // 128 nodes per bucket
#define MAX_BKT   512               // >= ceil(50000/128)+1

typedef __attribute__((ext_vector_type(8))) short short8;
typedef __attribute__((ext_vector_type(4))) float float4v;

__device__ __forceinline__ unsigned short f2bf_rne(float f) {
    unsigned int u = __float_as_uint(f);
    u += 0x7FFFu + ((u >> 16) & 1u);
    return (unsigned short)(u >> 16);
}

// --- conv: flat fp32 -> bf16 for [feature (nf elems)] ++ [W (nw elems)] ---
__global__ __launch_bounds__(256) void conv_bf16_kernel(
    const float* __restrict__ feat, const float* __restrict__ W,
    unsigned short* __restrict__ out_bf, long nf, long nw)
{
    long i4 = ((long)blockIdx.x * 256 + threadIdx.x) * 4;
    if (i4 >= nf + nw) return;          // nf, nw both multiples of 4
    const float* srcp = (i4 < nf) ? (feat + i4) : (W + (i4 - nf));
    float4 v = *(const float4*)srcp;
    ushort4 o;
    o.x = f2bf_rne(v.x); o.y = f2bf_rne(v.y);
    o.z = f2bf_rne(v.z); o.w = f2bf_rne(v.w);
    *(ushort4*)(out_bf + i4) = o;
}

// --- p_hist: per-block LDS histogram of dst buckets -> global bucket_cnt ---
__global__ __launch_bounds__(256) void p_hist_kernel(
    const int* __restrict__ dst, int* __restrict__ bucket_cnt,
    int n_edges, int nb, int chunk)
{
    __shared__ int lcnt[MAX_BKT];
    int tid = threadIdx.x;
    int e0  = blockIdx.x * chunk;
    int e1  = min(e0 + chunk, n_edges);

    for (int i = tid; i < nb; i += 256) lcnt[i] = 0;
    __syncthreads();
    for (int e = e0 + tid; e < e1; e += 256)
        atomicAdd(&lcnt[dst[e] >> BKT_SHIFT], 1);
    __syncthreads();
    for (int i = tid; i < nb; i += 256) {
        int c = lcnt[i];
        if (c) atomicAdd(&bucket_cnt[i], c);
    }
}

// --- p_scan: one wave, 8 buckets/lane; writes bucket_off[0..nb] + cursor ---
__global__ __launch_bounds__(64) void p_scan_kernel(
    const int* __restrict__ bucket_cnt, int* __restrict__ bucket_off,
    int* __restrict__ bucket_cursor, int nb)
{
    int lane = threadIdx.x;
    const int PER = 8;
    int base = lane * PER;
    int v[PER];
    int sum = 0;
    #pragma unroll
    for (int j = 0; j < PER; j++) {
        v[j] = (base + j < nb) ? bucket_cnt[base + j] : 0;
        sum += v[j];
    }
    int x = sum;
    #pragma unroll
    for (int off = 1; off < 64; off <<= 1) {
        int y = __shfl_up(x, off, 64);
        if (lane >= off) x += y;
    }
    int run = x - sum;
    #pragma unroll
    for (int j = 0; j < PER; j++) {
        int idx = base + j;
        if (idx <= nb) {
            bucket_off[idx] = run;
            if (idx < nb) bucket_cursor[idx] = run;
        }
        run += v[j];
    }
}

// --- p_scatter: partition edges into bucket regions as (dst,src) pairs ---
__global__ __launch_bounds__(256) void p_scatter_kernel(
    const int* __restrict__ src, const int* __restrict__ dst,
    int* __restrict__ bucket_cursor, int2* __restrict__ pairs,
    int n_edges, int nb, int chunk)
{
    __shared__ int lcnt[MAX_BKT];
    __shared__ int lcur[MAX_BKT];
    int tid = threadIdx.x;
    int e0  = blockIdx.x * chunk;
    int e1  = min(e0 + chunk, n_edges);

    for (int i = tid; i < nb; i += 256) lcnt[i] = 0;
    __syncthreads();
    for (int e = e0 + tid; e < e1; e += 256)
        atomicAdd(&lcnt[dst[e] >> BKT_SHIFT], 1);
    __syncthreads();
    for (int i = tid; i < nb; i += 256) {
        int c = lcnt[i];
        lcur[i] = c ? atomicAdd(&bucket_cursor[i], c) : 0;
    }
    __syncthreads();
    for (int e = e0 + tid; e < e1; e += 256) {
        int d = dst[e];
        int s = src[e];
        int pos = atomicAdd(&lcur[d >> BKT_SHIFT], 1);
        pairs[pos] = make_int2(d, s);
    }
}

// --- local_csr: per bucket (128 nodes) exact CSR via LDS hist + scan ---
__global__ __launch_bounds__(256) void local_csr_kernel(
    const int2* __restrict__ pairs, const int* __restrict__ bucket_off,
    int* __restrict__ offs, int* __restrict__ src_sorted,
    int n_nodes, int n_edges)
{
    __shared__ int hist[128];
    __shared__ int excl[128];
    __shared__ int curs[128];
    int b   = blockIdx.x;
    int tid = threadIdx.x;
    int node_base = b << BKT_SHIFT;
    int bstart = bucket_off[b];
    int bend   = bucket_off[b + 1];

    if (tid < 128) hist[tid] = 0;
    __syncthreads();
    for (int i = bstart + tid; i < bend; i += 256)
        atomicAdd(&hist[pairs[i].x - node_base], 1);
    __syncthreads();
    if (tid < 64) {
        int v0 = hist[2 * tid];
        int v1 = hist[2 * tid + 1];
        int s  = v0 + v1;
        int x  = s;
        #pragma unroll
        for (int off = 1; off < 64; off <<= 1) {
            int y = __shfl_up(x, off, 64);
            if (tid >= off) x += y;
        }
        int e0 = x - s;
        excl[2 * tid]     = e0;
        excl[2 * tid + 1] = e0 + v0;
    }
    __syncthreads();
    if (tid < 128) {
        int pos = bstart + excl[tid];
        int node = node_base + tid;
        if (node < n_nodes) offs[node] = pos;
        curs[tid] = pos;
    }
    __syncthreads();
    for (int i = bstart + tid; i < bend; i += 256) {
        int2 p = pairs[i];
        int pos = atomicAdd(&curs[p.x - node_base], 1);
        src_sorted[pos] = p.y;
    }
    if (b == 0 && tid == 0) offs[n_nodes] = n_edges;
}

// --- FUSED gather + MFMA projection ---
// Block = 4 waves = 64 nodes. Wave w gathers rows w*16..w*16+15 into LDS
// (bf16, row stride 136 elems = 272 B -> 2-way bank alias = free), fp32
// accumulation in registers. Then each wave MFMAs its own 16 rows against
// all 128 output cols (8 n-tiles x 4 chained K-steps), bias, fp32 store.
#define HT_STRIDE 136

__global__ __launch_bounds__(256) void gcn_gather_mm_kernel(
    const float* __restrict__ feat_f32,
    const unsigned short* __restrict__ feat_bf, int use_bf16,
    const int* __restrict__ offs, const int* __restrict__ src_sorted,
    const unsigned short* __restrict__ w_bf, const float* __restrict__ bias,
    float* __restrict__ out, int n_nodes)
{
    __shared__ unsigned short htile[64 * HT_STRIDE];   // 17408 B

    int tid   = threadIdx.x;
    int lane  = tid & 63;
    int w     = tid >> 6;          // wave id 0..3
    int m0    = w << 4;            // this wave's local row base
    int node0 = blockIdx.x * 64;

    // ---- Phase 1: gather 16 rows (each lane owns cols 2*lane, 2*lane+1) ----
    for (int t = 0; t < 16; t++) {
        int node = node0 + m0 + t;
        float accx = 0.f, accy = 0.f;
        if (node < n_nodes) {
            int beg = offs[node];
            int end = offs[node + 1];
            int i = beg;
            if (use_bf16) {
                for (; i + 3 < end; i += 4) {
                    int s0 = src_sorted[i],     s1 = src_sorted[i + 1];
                    int s2 = src_sorted[i + 2], s3 = src_sorted[i + 3];
                    unsigned int u0 = *(const unsigned int*)(feat_bf + (size_t)s0 * 128 + lane * 2);
                    unsigned int u1 = *(const unsigned int*)(feat_bf + (size_t)s1 * 128 + lane * 2);
                    unsigned int u2 = *(const unsigned int*)(feat_bf + (size_t)s2 * 128 + lane * 2);
                    unsigned int u3 = *(const unsigned int*)(feat_bf + (size_t)s3 * 128 + lane * 2);
                    accx += __uint_as_float(u0 << 16) + __uint_as_float(u1 << 16)
                          + __uint_as_float(u2 << 16) + __uint_as_float(u3 << 16);
                    accy += __uint_as_float(u0 & 0xFFFF0000u) + __uint_as_float(u1 & 0xFFFF0000u)
                          + __uint_as_float(u2 & 0xFFFF0000u) + __uint_as_float(u3 & 0xFFFF0000u);
                }
                for (; i < end; ++i) {
                    unsigned int u = *(const unsigned int*)(feat_bf + (size_t)src_sorted[i] * 128 + lane * 2);
                    accx += __uint_as_float(u << 16);
                    accy += __uint_as_float(u & 0xFFFF0000u);
                }
            } else {
                for (; i + 3 < end; i += 4) {
                    int s0 = src_sorted[i],     s1 = src_sorted[i + 1];
                    int s2 = src_sorted[i + 2], s3 = src_sorted[i + 3];
                    float2 v0 = ((const float2*)(feat_f32 + (size_t)s0 * 128))[lane];
                    float2 v1 = ((const float2*)(feat_f32 + (size_t)s1 * 128))[lane];
                    float2 v2 = ((const float2*)(feat_f32 + (size_t)s2 * 128))[lane];
                    float2 v3 = ((const float2*)(feat_f32 + (size_t)s3 * 128))[lane];
                    accx += (v0.x + v1.x) + (v2.x + v3.x);
                    accy += (v0.y + v1.y) + (v2.y + v3.y);
                }
                for (; i < end; ++i) {
                    float2 v = ((const float2*)(feat_f32 + (size_t)src_sorted[i] * 128))[lane];
                    accx += v.x;
                    accy += v.y;
                }
            }
        }
        unsigned int px = (unsigned int)f2bf_rne(accx);
        unsigned int py = (unsigned int)f2bf_rne(accy) << 16;
        *(unsigned int*)(htile + (m0 + t) * HT_STRIDE + lane * 2) = px | py;
    }

    __syncthreads();

    // ---- Phase 2: D[16x16] = A[16x32] * B[32x16] over 4 K-steps, 8 n-tiles.
    // A: lane holds h[m = lane&15][k = quad*8 + j]  (16B ds_read, 2-way free)
    // B: lane holds W[n = lane&15][k = quad*8 + j]  (16B global, line-packed)
    // D: col = lane&15, row = quad*4 + reg          (verified m89/m91 layout)
    int lane15 = lane & 15;
    int quad   = lane >> 4;

    short8 afrag[4];
    #pragma unroll
    for (int kk = 0; kk < 4; kk++)
        afrag[kk] = *(const short8*)(htile + (m0 + lane15) * HT_STRIDE + kk * 32 + quad * 8);

    for (int t = 0; t < 8; t++) {
        float4v acc = {0.f, 0.f, 0.f, 0.f};
        #pragma unroll
        for (int kk = 0; kk < 4; kk++) {
            short8 bfrag = *(const short8*)(w_bf + (size_t)(t * 16 + lane15) * 128 + kk * 32 + quad * 8);
            acc = __builtin_amdgcn_mfma_f32_16x16x32_bf16(afrag[kk], bfrag, acc, 0, 0, 0);
        }
        float bv = bias[t * 16 + lane15];
        #pragma unroll
        for (int r = 0; r < 4; r++) {
            int row = node0 + m0 + quad * 4 + r;
            if (row < n_nodes)
                out[(size_t)row * 128 + t * 16 + lane15] = acc[r] + bv;
        }
    }
}

extern "C" void kernel_launch(void* const* d_in, const int* in_sizes, int n_in,
                              void* d_out, int out_size, void* d_ws, size_t ws_size,
                              hipStream_t stream) {
    const float* feature = (const float*)d_in[0];
    const int*   src     = (const int*)d_in[1];
    const int*   dst     = (const int*)d_in[2];
    const float* W       = (const float*)d_in[3];
    const float* b       = (const float*)d_in[4];

    const int D  = 128;
    int n_nodes  = in_sizes[0] / D;
    int n_edges  = in_sizes[1];
    int nb       = (n_nodes + 127) >> BKT_SHIFT;

    float* out = (float*)d_out;

    long nf = (long)n_nodes * D;      // feature elems (mult of 4)
    long nw = (long)D * D;            // W elems (16384)

    // ws layout: [feature_bf nf? ] [w_bf nw] [pairs E int2] [src_sorted E]
    //            [offs N+1] [bucket_cnt 512] [bucket_off 513] [bucket_cur 512]
    size_t tail_bytes = (size_t)n_edges * 8 + (size_t)n_edges * 4 +
                        (size_t)(n_nodes + 1) * 4 + (size_t)(3 * MAX_BKT + 1) * 4;
    size_t need_full  = (size_t)(nf + nw) * 2 + tail_bytes;
    int use_bf16 = (ws_size >= need_full) ? 1 : 0;   // constant across calls

    unsigned short* bf_base    = (unsigned short*)d_ws;
    long            nf_eff     = use_bf16 ? nf : 0;
    unsigned short* feature_bf = bf_base;            // valid only if use_bf16
    unsigned short* w_bf       = bf_base + nf_eff;
    int2* pairs        = (int2*)(bf_base + nf_eff + nw);
    int* src_sorted    = (int*)(pairs + n_edges);
    int* offs          = src_sorted + n_edges;
    int* bucket_cnt    = offs + (n_nodes + 1);
    int* bucket_off    = bucket_cnt + MAX_BKT;
    int* bucket_cursor = bucket_off + (MAX_BKT + 1);

    hipMemsetAsync(bucket_cnt, 0, (size_t)nb * sizeof(int), stream);

    // bf16 conversion of feature (optional) + W
    {
        long total = nf_eff + nw;
        int blocks = (int)((total / 4 + 255) / 256);
        conv_bf16_kernel<<<blocks, 256, 0, stream>>>(feature, W, bf_base, nf_eff, nw);
    }

    const int NPART = 128;
    int chunk = (n_edges + NPART - 1) / NPART;

    p_hist_kernel<<<NPART, 256, 0, stream>>>(dst, bucket_cnt, n_edges, nb, chunk);
    p_scan_kernel<<<1, 64, 0, stream>>>(bucket_cnt, bucket_off, bucket_cursor, nb);
    p_scatter_kernel<<<NPART, 256, 0, stream>>>(src, dst, bucket_cursor, pairs,
                                                n_edges, nb, chunk);
    local_csr_kernel<<<nb, 256, 0, stream>>>(pairs, bucket_off, offs, src_sorted,
                                             n_nodes, n_edges);

    {
        int blocks = (n_nodes + 63) / 64;
        gcn_gather_mm_kernel<<<blocks, 256, 0, stream>>>(
            feature, feature_bf, use_bf16, offs, src_sorted, w_bf, b, out, n_nodes);
    }
}